// Round 7
// baseline (538.924 us; speedup 1.0000x reference)
//
#include <hip/hip_runtime.h>
#include <math.h>

#define NEG_SLOPE 0.2f

static inline int cdiv(int a, int b) { return (a + b - 1) / b; }

// ---------------- CSR build: LDS radix partition by dst bucket --------------
// bucket = 256 consecutive dst nodes; packed entry = (src<<8) | (dst&255).
// Requires N <= 65536 (here N=50000) and NBK <= 256 (196).
#define BCAP 12288            // per-bucket slab capacity (avg fill ~8450)
#define PT_THREADS 512
#define PT_EPT 16
#define PT_CHUNK (PT_THREADS * PT_EPT)   // 8192 edges per block

__global__ __launch_bounds__(PT_THREADS)
void partition_kernel(const int* __restrict__ src, const int* __restrict__ dst,
                      unsigned* __restrict__ gcursor, unsigned* __restrict__ slab,
                      int E, int ET, int NBK) {
    __shared__ int hist[256];
    __shared__ int lbase[256];
    __shared__ int lcur[256];
    __shared__ int gbase[256];
    __shared__ unsigned stage[PT_CHUNK];
    __shared__ unsigned char binof[PT_CHUNK];

    int base = blockIdx.x * PT_CHUNK;
    int cnt = min(PT_CHUNK, ET - base);

    unsigned vals[PT_EPT];
    short bins[PT_EPT];

    for (int i = threadIdx.x; i < 256; i += PT_THREADS) hist[i] = 0;
    __syncthreads();

#pragma unroll
    for (int i = 0; i < PT_EPT; ++i) {
        int e = base + threadIdx.x + i * PT_THREADS;
        bins[i] = -1;
        if (e < ET) {
            int s = (e < E) ? src[e] : (e - E);
            int d = (e < E) ? dst[e] : (e - E);
            int b = d >> 8;
            vals[i] = ((unsigned)s << 8) | (unsigned)(d & 255);
            bins[i] = (short)b;
            atomicAdd(&hist[b], 1);
        }
    }
    __syncthreads();
    if (threadIdx.x < 256) lbase[threadIdx.x] = hist[threadIdx.x];
    __syncthreads();
    for (int off = 1; off < 256; off <<= 1) {
        int t = 0;
        if (threadIdx.x < 256 && threadIdx.x >= off) t = lbase[threadIdx.x - off];
        __syncthreads();
        if (threadIdx.x < 256) lbase[threadIdx.x] += t;
        __syncthreads();
    }
    if (threadIdx.x < 256) {
        lbase[threadIdx.x] -= hist[threadIdx.x];   // exclusive
        lcur[threadIdx.x] = lbase[threadIdx.x];
        gbase[threadIdx.x] = ((int)threadIdx.x < NBK && hist[threadIdx.x] > 0)
            ? (int)atomicAdd(&gcursor[threadIdx.x], (unsigned)hist[threadIdx.x]) : 0;
    }
    __syncthreads();
#pragma unroll
    for (int i = 0; i < PT_EPT; ++i) {
        if (bins[i] >= 0) {
            int p = atomicAdd(&lcur[bins[i]], 1);
            stage[p] = vals[i];
            binof[p] = (unsigned char)bins[i];
        }
    }
    __syncthreads();
    for (int j = threadIdx.x; j < cnt; j += PT_THREADS) {
        int b = binof[j];
        int idx = gbase[b] + (j - lbase[b]);
        if (idx < BCAP) slab[(size_t)b * BCAP + idx] = stage[j];
    }
}

// one block per bucket: degree + local offsets + stable in-place sort by dst
__global__ __launch_bounds__(512)
void finalize_kernel(const unsigned* __restrict__ gcursor, unsigned* __restrict__ slab,
                     int* __restrict__ offs, int* __restrict__ deg, int N) {
    __shared__ int lhist[256];
    __shared__ int loff[256];
    __shared__ int lcur[256];
    __shared__ unsigned stage[BCAP];
    int b = blockIdx.x;
    int cnt = min((int)gcursor[b], BCAP);
    int d0 = b << 8;
    int nd = min(256, N - d0);
    size_t sb = (size_t)b * BCAP;

    for (int i = threadIdx.x; i < 256; i += 512) lhist[i] = 0;
    __syncthreads();
    for (int i = threadIdx.x; i < cnt; i += 512)
        atomicAdd(&lhist[slab[sb + i] & 255u], 1);
    __syncthreads();
    if (threadIdx.x < 256) loff[threadIdx.x] = lhist[threadIdx.x];
    __syncthreads();
    for (int off = 1; off < 256; off <<= 1) {
        int t = 0;
        if (threadIdx.x < 256 && threadIdx.x >= off) t = loff[threadIdx.x - off];
        __syncthreads();
        if (threadIdx.x < 256) loff[threadIdx.x] += t;
        __syncthreads();
    }
    if (threadIdx.x < 256) {
        loff[threadIdx.x] -= lhist[threadIdx.x];   // exclusive
        lcur[threadIdx.x] = loff[threadIdx.x];
        if ((int)threadIdx.x < nd) {
            offs[d0 + threadIdx.x] = (int)sb + loff[threadIdx.x];
            deg[d0 + threadIdx.x] = lhist[threadIdx.x];
        }
    }
    __syncthreads();
    for (int i = threadIdx.x; i < cnt; i += 512) {
        unsigned v = slab[sb + i];
        int p = atomicAdd(&lcur[v & 255u], 1);
        stage[p] = v >> 8;
    }
    __syncthreads();
    for (int i = threadIdx.x; i < cnt; i += 512)
        slab[sb + i] = stage[i];
}

// ============ dense GEMM + fused attention-logit epilogue ===================
template <int CIN, int COUT, int H>
__global__ void gemm_logits_kernel(const float* __restrict__ in, const float* __restrict__ W,
                                   const float* __restrict__ a_s, const float* __restrict__ a_d,
                                   float* __restrict__ out, float* __restrict__ als,
                                   float* __restrict__ ald, int N) {
    constexpr int D = COUT / H;
    constexpr int TPN = COUT / 4;    // threads per node
    constexpr int NPB = 256 / TPN;   // nodes per block
    __shared__ float xs[NPB * CIN];
    __shared__ float lsum[2][NPB][H];
    int n0 = blockIdx.x * NPB;
    for (int i = threadIdx.x * 4; i < NPB * CIN; i += 256 * 4) {
        int n = n0 + i / CIN;
        float4 v = make_float4(0.f, 0.f, 0.f, 0.f);
        if (n < N) v = *(const float4*)&in[(size_t)n0 * CIN + i];
        *(float4*)&xs[i] = v;
    }
    for (int i = threadIdx.x; i < 2 * NPB * H; i += 256) ((float*)lsum)[i] = 0.f;
    __syncthreads();
    int tn = threadIdx.x / TPN;
    int tc = (threadIdx.x % TPN) * 4;
    int n = n0 + tn;
    if (n < N) {
        const float* xr = xs + tn * CIN;
        float4 a = make_float4(0.f, 0.f, 0.f, 0.f);
#pragma unroll 8
        for (int k = 0; k < CIN; ++k) {
            float xv = xr[k];
            float4 wv = *(const float4*)&W[k * COUT + tc];
            a.x = fmaf(xv, wv.x, a.x);
            a.y = fmaf(xv, wv.y, a.y);
            a.z = fmaf(xv, wv.z, a.z);
            a.w = fmaf(xv, wv.w, a.w);
        }
        *(float4*)&out[(size_t)n * COUT + tc] = a;
        int h = tc / D;
        int dd = tc % D;
        const float* asr = a_s + h * D + dd;
        const float* adr = a_d + h * D + dd;
        float p1 = a.x * asr[0] + a.y * asr[1] + a.z * asr[2] + a.w * asr[3];
        float p2 = a.x * adr[0] + a.y * adr[1] + a.z * adr[2] + a.w * adr[3];
        atomicAdd(&lsum[0][tn][h], p1);
        atomicAdd(&lsum[1][tn][h], p2);
    }
    __syncthreads();
    for (int i = threadIdx.x; i < NPB * H; i += 256) {
        int tn2 = i / H, h2 = i % H;
        int n2 = n0 + tn2;
        if (n2 < N) {
            als[n2 * H + h2] = lsum[0][tn2][h2];
            ald[n2 * H + h2] = lsum[1][tn2][h2];
        }
    }
}

// ===== H=8,D=8 specialized aggregate: phase-2 batches 8 edges/iteration =====
// ONE WAVE PER NODE. lane = (edge_slot el = lane>>3, head hl = lane&7).
// Phase 1: per-lane online (m,s) over edges el, el+8, ...; shfl_xor merge.
// Phase 2: each iteration covers 8 edges; each lane computes ONE (edge,head)
// weight (1 als load + 1 exp for the wave), then shuffle-broadcasts (sn,w)
// to the accumulating layout lane=channel. No redundant exp, fewer VMEM.
template <bool RELU>
__global__ void gat_node8_kernel(const float* __restrict__ hfeat,
                                 const float* __restrict__ als, const float* __restrict__ ald,
                                 const int* __restrict__ offs, const int* __restrict__ deg,
                                 const int* __restrict__ csr_src,
                                 const float* __restrict__ bias,
                                 float* __restrict__ out, int N) {
    int lane = threadIdx.x & 63;
    int wid = threadIdx.x >> 6;
    int node = blockIdx.x * (blockDim.x >> 6) + wid;
    if (node >= N) return;
    int row = __builtin_amdgcn_readfirstlane(offs[node]);
    int cnt = __builtin_amdgcn_readfirstlane(deg[node]);

    int hl = lane & 7;          // head this lane evaluates logits for
    int el = lane >> 3;         // edge slot 0..7
    float xd = ald[node * 8 + hl];

    // ---------- phase 1: per-head (m, s) ----------
    float ml = -INFINITY, sl = 0.f;
    for (int k = el; k < cnt; k += 8) {
        int sn = csr_src[row + k];
        float x = als[sn * 8 + hl] + xd;
        x = (x > 0.f) ? x : NEG_SLOPE * x;
        float mn = fmaxf(ml, x);
        sl = sl * __expf(ml - mn) + __expf(x - mn);
        ml = mn;
    }
    for (int off = 8; off < 64; off <<= 1) {   // merge 8 edge slots
        float mo = __shfl_xor(ml, off);
        float so = __shfl_xor(sl, off);
        float mn = fmaxf(ml, mo);
        float t1 = (ml > -INFINITY) ? sl * __expf(ml - mn) : 0.f;
        float t2 = (mo > -INFINITY) ? so * __expf(mo - mn) : 0.f;
        sl = t1 + t2;
        ml = mn;
    }
    // lane now holds (m, s) for head hl (identical across el)

    // ---------- phase 2: 8 edges per iteration ----------
    int c = lane;               // output channel 0..63
    int h2 = lane >> 3;         // head of this channel (D=8)
    float s2 = __shfl(sl, h2);  // lane h2 holds head h2 (hl = lane&7)
    float acc = 0.f;
    for (int k = 0; k < cnt; k += 8) {
        int kk = k + el;
        int kc = (kk < cnt) ? kk : (cnt - 1);
        int sn_l = csr_src[row + kc];
        float x = als[sn_l * 8 + hl] + xd;
        x = (x > 0.f) ? x : NEG_SLOPE * x;
        float w_l = (kk < cnt) ? __expf(x - ml) : 0.f;
#pragma unroll
        for (int e = 0; e < 8; ++e) {
            int srcl = (e << 3) + h2;          // lane holding (edge e, head h2)
            int sn_e = __shfl(sn_l, srcl);
            float w_e = __shfl(w_l, srcl);
            acc = fmaf(w_e, hfeat[(size_t)sn_e * 64 + c], acc);
        }
    }
    float v = acc / s2 + bias[c];
    if (RELU) v = fmaxf(v, 0.f);
    out[(size_t)node * 64 + c] = v;
}

// ===== generic per-node GAT (used for layer 4: H=1, D=16) ==================
template <int H, int D, bool RELU>
__global__ void gat_node_kernel(const float* __restrict__ hfeat,
                                const float* __restrict__ als, const float* __restrict__ ald,
                                const int* __restrict__ offs, const int* __restrict__ deg,
                                const int* __restrict__ csr_src,
                                const float* __restrict__ bias,
                                float* __restrict__ out, int N) {
    constexpr int HD = H * D;
    constexpr int ES = 64 / H;    // phase-1 edge slots
    constexpr int EG = 64 / HD;   // phase-2 edge groups
    int lane = threadIdx.x & 63;
    int wid = threadIdx.x >> 6;
    int node = blockIdx.x * (blockDim.x >> 6) + wid;
    if (node >= N) return;
    int row = __builtin_amdgcn_readfirstlane(offs[node]);
    int cnt = __builtin_amdgcn_readfirstlane(deg[node]);

    int h1 = lane & (H - 1);
    float xd1 = ald[node * H + h1];
    float ml = -INFINITY, sl = 0.f;
    for (int k = lane / H; k < cnt; k += ES) {
        int sn = csr_src[row + k];
        float x = als[sn * H + h1] + xd1;
        x = (x > 0.f) ? x : NEG_SLOPE * x;
        float mn = fmaxf(ml, x);
        sl = sl * __expf(ml - mn) + __expf(x - mn);
        ml = mn;
    }
    for (int off = H; off < 64; off <<= 1) {
        float mo = __shfl_xor(ml, off);
        float so = __shfl_xor(sl, off);
        float mn = fmaxf(ml, mo);
        float t1 = (ml > -INFINITY) ? sl * __expf(ml - mn) : 0.f;
        float t2 = (mo > -INFINITY) ? so * __expf(mo - mn) : 0.f;
        sl = t1 + t2;
        ml = mn;
    }

    int c = lane & (HD - 1);
    int h2 = c / D;
    float m2 = __shfl(ml, h2);
    float s2 = __shfl(sl, h2);
    float xd2 = ald[node * H + h2];
    float a0 = 0.f, a1 = 0.f, a2 = 0.f, a3 = 0.f;
    int k = lane / HD;
    for (; k + 3 * EG < cnt; k += 4 * EG) {
        int sn0 = csr_src[row + k];
        int sn1 = csr_src[row + k + EG];
        int sn2 = csr_src[row + k + 2 * EG];
        int sn3 = csr_src[row + k + 3 * EG];
        float x0 = als[sn0 * H + h2] + xd2;
        float x1 = als[sn1 * H + h2] + xd2;
        float x2 = als[sn2 * H + h2] + xd2;
        float x3 = als[sn3 * H + h2] + xd2;
        x0 = (x0 > 0.f) ? x0 : NEG_SLOPE * x0;
        x1 = (x1 > 0.f) ? x1 : NEG_SLOPE * x1;
        x2 = (x2 > 0.f) ? x2 : NEG_SLOPE * x2;
        x3 = (x3 > 0.f) ? x3 : NEG_SLOPE * x3;
        float w0 = __expf(x0 - m2);
        float w1 = __expf(x1 - m2);
        float w2 = __expf(x2 - m2);
        float w3 = __expf(x3 - m2);
        a0 = fmaf(w0, hfeat[(size_t)sn0 * HD + c], a0);
        a1 = fmaf(w1, hfeat[(size_t)sn1 * HD + c], a1);
        a2 = fmaf(w2, hfeat[(size_t)sn2 * HD + c], a2);
        a3 = fmaf(w3, hfeat[(size_t)sn3 * HD + c], a3);
    }
    for (; k < cnt; k += EG) {
        int sn = csr_src[row + k];
        float x = als[sn * H + h2] + xd2;
        x = (x > 0.f) ? x : NEG_SLOPE * x;
        a0 = fmaf(__expf(x - m2), hfeat[(size_t)sn * HD + c], a0);
    }
    float acc = (a0 + a1) + (a2 + a3);
    for (int off = HD; off < 64; off <<= 1) acc += __shfl_xor(acc, off);
    if (lane < HD) {
        float v = acc / s2 + bias[c];
        if (RELU) v = fmaxf(v, 0.f);
        out[(size_t)node * HD + c] = v;
    }
}

// ============================================================================

extern "C" void kernel_launch(void* const* d_in, const int* in_sizes, int n_in,
                              void* d_out, int out_size, void* d_ws, size_t ws_size,
                              hipStream_t stream) {
    const float* x   = (const float*)d_in[0];
    const int*   ei  = (const int*)d_in[1];
    const float* W1  = (const float*)d_in[2];
    const float* a1s = (const float*)d_in[3];
    const float* a1d = (const float*)d_in[4];
    const float* b1  = (const float*)d_in[5];
    const float* W2  = (const float*)d_in[6];
    const float* a2s = (const float*)d_in[7];
    const float* a2d = (const float*)d_in[8];
    const float* b2  = (const float*)d_in[9];
    const float* W3  = (const float*)d_in[10];
    const float* a3s = (const float*)d_in[11];
    const float* a3d = (const float*)d_in[12];
    const float* b3  = (const float*)d_in[13];
    const float* W4  = (const float*)d_in[14];
    const float* a4s = (const float*)d_in[15];
    const float* a4d = (const float*)d_in[16];
    const float* b4  = (const float*)d_in[17];

    const int N = in_sizes[0] / 128;  // 50000
    const int E = in_sizes[1] / 2;    // 1600000
    const int ET = E + N;             // + self loops
    const int* src = ei;
    const int* dst = ei + E;
    const int NBK = (N + 255) >> 8;   // 196 buckets of 256 dst nodes

    // ---- workspace layout ----
    float* hb    = (float*)d_ws;                    // N*64
    float* bufA  = hb + (size_t)N * 64;             // N*64
    float* als   = bufA + (size_t)N * 64;           // N*8
    float* ald   = als + (size_t)N * 8;             // N*8
    int* offs    = (int*)(ald + (size_t)N * 8);     // N
    int* deg     = offs + N;                        // N
    unsigned* gcursor = (unsigned*)(deg + N);       // 256 (memset 0)
    unsigned* slab = gcursor + 256;                 // NBK*BCAP (csr in place)
    float* out = (float*)d_out;                     // N*16

    const int TB = 256;
    const int NODE_BLOCKS = cdiv(N, 4);  // one wave per node, 4 waves/block

    // ---- build dst-CSR: radix partition + per-bucket finalize ----
    hipMemsetAsync(gcursor, 0, 256 * 4, stream);
    partition_kernel<<<cdiv(ET, PT_CHUNK), PT_THREADS, 0, stream>>>(src, dst, gcursor, slab, E, ET, NBK);
    finalize_kernel<<<NBK, 512, 0, stream>>>(gcursor, slab, offs, deg, N);
    const int* csr_src = (const int*)slab;

    // ---- layer 1: x[N,128] -> hb -> bufA ----
    gemm_logits_kernel<128, 64, 8><<<cdiv(N, 16), TB, 0, stream>>>(x, W1, a1s, a1d, hb, als, ald, N);
    gat_node8_kernel<true><<<NODE_BLOCKS, TB, 0, stream>>>(hb, als, ald, offs, deg, csr_src, b1, bufA, N);

    // ---- layer 2: bufA -> hb -> bufA ----
    gemm_logits_kernel<64, 64, 8><<<cdiv(N, 16), TB, 0, stream>>>(bufA, W2, a2s, a2d, hb, als, ald, N);
    gat_node8_kernel<true><<<NODE_BLOCKS, TB, 0, stream>>>(hb, als, ald, offs, deg, csr_src, b2, bufA, N);

    // ---- layer 3: bufA -> hb -> bufA ----
    gemm_logits_kernel<64, 64, 8><<<cdiv(N, 16), TB, 0, stream>>>(bufA, W3, a3s, a3d, hb, als, ald, N);
    gat_node8_kernel<true><<<NODE_BLOCKS, TB, 0, stream>>>(hb, als, ald, offs, deg, csr_src, b3, bufA, N);

    // ---- layer 4: bufA -> hb -> d_out (H=1, D=16, no relu) ----
    gemm_logits_kernel<64, 16, 1><<<cdiv(N, 64), TB, 0, stream>>>(bufA, W4, a4s, a4d, hb, als, ald, N);
    gat_node_kernel<1, 16, false><<<NODE_BLOCKS, TB, 0, stream>>>(hb, als, ald, offs, deg, csr_src, b4, out, N);
}

// Round 8
// 511.621 us; speedup vs baseline: 1.0534x; 1.0534x over previous
//
#include <hip/hip_runtime.h>
#include <hip/hip_bf16.h>
#include <math.h>

#define NEG_SLOPE 0.2f

static inline int cdiv(int a, int b) { return (a + b - 1) / b; }

// ---------------- CSR build: LDS radix partition by dst bucket --------------
// bucket = 256 consecutive dst nodes; packed entry = (src<<8) | (dst&255).
// Requires N <= 65536 (here N=50000) and NBK <= 256 (196).
#define BCAP 12288            // per-bucket slab capacity (avg fill ~8450)
#define PT_THREADS 512
#define PT_EPT 16
#define PT_CHUNK (PT_THREADS * PT_EPT)   // 8192 edges per block

__global__ __launch_bounds__(PT_THREADS)
void partition_kernel(const int* __restrict__ src, const int* __restrict__ dst,
                      unsigned* __restrict__ gcursor, unsigned* __restrict__ slab,
                      int E, int ET, int NBK) {
    __shared__ int hist[256];
    __shared__ int lbase[256];
    __shared__ int lcur[256];
    __shared__ int gbase[256];
    __shared__ unsigned stage[PT_CHUNK];
    __shared__ unsigned char binof[PT_CHUNK];

    int base = blockIdx.x * PT_CHUNK;
    int cnt = min(PT_CHUNK, ET - base);

    unsigned vals[PT_EPT];
    short bins[PT_EPT];

    for (int i = threadIdx.x; i < 256; i += PT_THREADS) hist[i] = 0;
    __syncthreads();

#pragma unroll
    for (int i = 0; i < PT_EPT; ++i) {
        int e = base + threadIdx.x + i * PT_THREADS;
        bins[i] = -1;
        if (e < ET) {
            int s = (e < E) ? src[e] : (e - E);
            int d = (e < E) ? dst[e] : (e - E);
            int b = d >> 8;
            vals[i] = ((unsigned)s << 8) | (unsigned)(d & 255);
            bins[i] = (short)b;
            atomicAdd(&hist[b], 1);
        }
    }
    __syncthreads();
    if (threadIdx.x < 256) lbase[threadIdx.x] = hist[threadIdx.x];
    __syncthreads();
    for (int off = 1; off < 256; off <<= 1) {
        int t = 0;
        if (threadIdx.x < 256 && threadIdx.x >= off) t = lbase[threadIdx.x - off];
        __syncthreads();
        if (threadIdx.x < 256) lbase[threadIdx.x] += t;
        __syncthreads();
    }
    if (threadIdx.x < 256) {
        lbase[threadIdx.x] -= hist[threadIdx.x];   // exclusive
        lcur[threadIdx.x] = lbase[threadIdx.x];
        gbase[threadIdx.x] = ((int)threadIdx.x < NBK && hist[threadIdx.x] > 0)
            ? (int)atomicAdd(&gcursor[threadIdx.x], (unsigned)hist[threadIdx.x]) : 0;
    }
    __syncthreads();
#pragma unroll
    for (int i = 0; i < PT_EPT; ++i) {
        if (bins[i] >= 0) {
            int p = atomicAdd(&lcur[bins[i]], 1);
            stage[p] = vals[i];
            binof[p] = (unsigned char)bins[i];
        }
    }
    __syncthreads();
    for (int j = threadIdx.x; j < cnt; j += PT_THREADS) {
        int b = binof[j];
        int idx = gbase[b] + (j - lbase[b]);
        if (idx < BCAP) slab[(size_t)b * BCAP + idx] = stage[j];
    }
}

// one block per bucket: degree + local offsets + stable in-place sort by dst
__global__ __launch_bounds__(512)
void finalize_kernel(const unsigned* __restrict__ gcursor, unsigned* __restrict__ slab,
                     int* __restrict__ offs, int* __restrict__ deg, int N) {
    __shared__ int lhist[256];
    __shared__ int loff[256];
    __shared__ int lcur[256];
    __shared__ unsigned stage[BCAP];
    int b = blockIdx.x;
    int cnt = min((int)gcursor[b], BCAP);
    int d0 = b << 8;
    int nd = min(256, N - d0);
    size_t sb = (size_t)b * BCAP;

    for (int i = threadIdx.x; i < 256; i += 512) lhist[i] = 0;
    __syncthreads();
    for (int i = threadIdx.x; i < cnt; i += 512)
        atomicAdd(&lhist[slab[sb + i] & 255u], 1);
    __syncthreads();
    if (threadIdx.x < 256) loff[threadIdx.x] = lhist[threadIdx.x];
    __syncthreads();
    for (int off = 1; off < 256; off <<= 1) {
        int t = 0;
        if (threadIdx.x < 256 && threadIdx.x >= off) t = loff[threadIdx.x - off];
        __syncthreads();
        if (threadIdx.x < 256) loff[threadIdx.x] += t;
        __syncthreads();
    }
    if (threadIdx.x < 256) {
        loff[threadIdx.x] -= lhist[threadIdx.x];   // exclusive
        lcur[threadIdx.x] = loff[threadIdx.x];
        if ((int)threadIdx.x < nd) {
            offs[d0 + threadIdx.x] = (int)sb + loff[threadIdx.x];
            deg[d0 + threadIdx.x] = lhist[threadIdx.x];
        }
    }
    __syncthreads();
    for (int i = threadIdx.x; i < cnt; i += 512) {
        unsigned v = slab[sb + i];
        int p = atomicAdd(&lcur[v & 255u], 1);
        stage[p] = v >> 8;
    }
    __syncthreads();
    for (int i = threadIdx.x; i < cnt; i += 512)
        slab[sb + i] = stage[i];
}

// ============ dense GEMM + fused attention-logit epilogue ===================
// BF16OUT: write feature matrix as bf16 (halves gather traffic downstream);
// logits always computed from fp32 accumulators.
template <int CIN, int COUT, int H, bool BF16OUT>
__global__ void gemm_logits_kernel(const float* __restrict__ in, const float* __restrict__ W,
                                   const float* __restrict__ a_s, const float* __restrict__ a_d,
                                   void* __restrict__ outv, float* __restrict__ als,
                                   float* __restrict__ ald, int N) {
    constexpr int D = COUT / H;
    constexpr int TPN = COUT / 4;    // threads per node
    constexpr int NPB = 256 / TPN;   // nodes per block
    __shared__ float xs[NPB * CIN];
    __shared__ float lsum[2][NPB][H];
    int n0 = blockIdx.x * NPB;
    for (int i = threadIdx.x * 4; i < NPB * CIN; i += 256 * 4) {
        int n = n0 + i / CIN;
        float4 v = make_float4(0.f, 0.f, 0.f, 0.f);
        if (n < N) v = *(const float4*)&in[(size_t)n0 * CIN + i];
        *(float4*)&xs[i] = v;
    }
    for (int i = threadIdx.x; i < 2 * NPB * H; i += 256) ((float*)lsum)[i] = 0.f;
    __syncthreads();
    int tn = threadIdx.x / TPN;
    int tc = (threadIdx.x % TPN) * 4;
    int n = n0 + tn;
    if (n < N) {
        const float* xr = xs + tn * CIN;
        float4 a = make_float4(0.f, 0.f, 0.f, 0.f);
#pragma unroll 8
        for (int k = 0; k < CIN; ++k) {
            float xv = xr[k];
            float4 wv = *(const float4*)&W[k * COUT + tc];
            a.x = fmaf(xv, wv.x, a.x);
            a.y = fmaf(xv, wv.y, a.y);
            a.z = fmaf(xv, wv.z, a.z);
            a.w = fmaf(xv, wv.w, a.w);
        }
        if (BF16OUT) {
            __hip_bfloat16* ob = (__hip_bfloat16*)outv;
            ushort4 u;
            u.x = __hip_bfloat16_raw(__float2bfloat16(a.x)).x;
            u.y = __hip_bfloat16_raw(__float2bfloat16(a.y)).x;
            u.z = __hip_bfloat16_raw(__float2bfloat16(a.z)).x;
            u.w = __hip_bfloat16_raw(__float2bfloat16(a.w)).x;
            *(ushort4*)&ob[(size_t)n * COUT + tc] = u;
        } else {
            float* of = (float*)outv;
            *(float4*)&of[(size_t)n * COUT + tc] = a;
        }
        int h = tc / D;
        int dd = tc % D;
        const float* asr = a_s + h * D + dd;
        const float* adr = a_d + h * D + dd;
        float p1 = a.x * asr[0] + a.y * asr[1] + a.z * asr[2] + a.w * asr[3];
        float p2 = a.x * adr[0] + a.y * adr[1] + a.z * adr[2] + a.w * adr[3];
        atomicAdd(&lsum[0][tn][h], p1);
        atomicAdd(&lsum[1][tn][h], p2);
    }
    __syncthreads();
    for (int i = threadIdx.x; i < NPB * H; i += 256) {
        int tn2 = i / H, h2 = i % H;
        int n2 = n0 + tn2;
        if (n2 < N) {
            als[n2 * H + h2] = lsum[0][tn2][h2];
            ald[n2 * H + h2] = lsum[1][tn2][h2];
        }
    }
}

// ===== H=8,D=8 specialized aggregate, bf16 feature gather ===================
// ONE WAVE PER NODE. lane = (edge_slot el = lane>>3, head hl = lane&7).
template <bool RELU>
__global__ void gat_node8_kernel(const __hip_bfloat16* __restrict__ hfeat,
                                 const float* __restrict__ als, const float* __restrict__ ald,
                                 const int* __restrict__ offs, const int* __restrict__ deg,
                                 const int* __restrict__ csr_src,
                                 const float* __restrict__ bias,
                                 float* __restrict__ out, int N) {
    int lane = threadIdx.x & 63;
    int wid = threadIdx.x >> 6;
    int node = blockIdx.x * (blockDim.x >> 6) + wid;
    if (node >= N) return;
    int row = __builtin_amdgcn_readfirstlane(offs[node]);
    int cnt = __builtin_amdgcn_readfirstlane(deg[node]);

    int hl = lane & 7;          // head this lane evaluates logits for
    int el = lane >> 3;         // edge slot 0..7
    float xd = ald[node * 8 + hl];

    // ---------- phase 1: per-head (m, s) ----------
    float ml = -INFINITY, sl = 0.f;
    for (int k = el; k < cnt; k += 8) {
        int sn = csr_src[row + k];
        float x = als[sn * 8 + hl] + xd;
        x = (x > 0.f) ? x : NEG_SLOPE * x;
        float mn = fmaxf(ml, x);
        sl = sl * __expf(ml - mn) + __expf(x - mn);
        ml = mn;
    }
    for (int off = 8; off < 64; off <<= 1) {   // merge 8 edge slots
        float mo = __shfl_xor(ml, off);
        float so = __shfl_xor(sl, off);
        float mn = fmaxf(ml, mo);
        float t1 = (ml > -INFINITY) ? sl * __expf(ml - mn) : 0.f;
        float t2 = (mo > -INFINITY) ? so * __expf(mo - mn) : 0.f;
        sl = t1 + t2;
        ml = mn;
    }

    // ---------- phase 2: 8 edges per iteration ----------
    int c = lane;               // output channel 0..63
    int h2 = lane >> 3;         // head of this channel (D=8)
    float s2 = __shfl(sl, h2);  // lane h2 holds head h2 (hl = lane&7)
    float acc = 0.f;
    for (int k = 0; k < cnt; k += 8) {
        int kk = k + el;
        int kc = (kk < cnt) ? kk : (cnt - 1);
        int sn_l = csr_src[row + kc];
        float x = als[sn_l * 8 + hl] + xd;
        x = (x > 0.f) ? x : NEG_SLOPE * x;
        float w_l = (kk < cnt) ? __expf(x - ml) : 0.f;
#pragma unroll
        for (int e = 0; e < 8; ++e) {
            int srcl = (e << 3) + h2;          // lane holding (edge e, head h2)
            int sn_e = __shfl(sn_l, srcl);
            float w_e = __shfl(w_l, srcl);
            float hv = __bfloat162float(hfeat[(size_t)sn_e * 64 + c]);
            acc = fmaf(w_e, hv, acc);
        }
    }
    float v = acc / s2 + bias[c];
    if (RELU) v = fmaxf(v, 0.f);
    out[(size_t)node * 64 + c] = v;
}

// ===== generic per-node GAT (layer 4: H=1, D=16, fp32 features) ============
template <int H, int D, bool RELU>
__global__ void gat_node_kernel(const float* __restrict__ hfeat,
                                const float* __restrict__ als, const float* __restrict__ ald,
                                const int* __restrict__ offs, const int* __restrict__ deg,
                                const int* __restrict__ csr_src,
                                const float* __restrict__ bias,
                                float* __restrict__ out, int N) {
    constexpr int HD = H * D;
    constexpr int ES = 64 / H;    // phase-1 edge slots
    constexpr int EG = 64 / HD;   // phase-2 edge groups
    int lane = threadIdx.x & 63;
    int wid = threadIdx.x >> 6;
    int node = blockIdx.x * (blockDim.x >> 6) + wid;
    if (node >= N) return;
    int row = __builtin_amdgcn_readfirstlane(offs[node]);
    int cnt = __builtin_amdgcn_readfirstlane(deg[node]);

    int h1 = lane & (H - 1);
    float xd1 = ald[node * H + h1];
    float ml = -INFINITY, sl = 0.f;
    for (int k = lane / H; k < cnt; k += ES) {
        int sn = csr_src[row + k];
        float x = als[sn * H + h1] + xd1;
        x = (x > 0.f) ? x : NEG_SLOPE * x;
        float mn = fmaxf(ml, x);
        sl = sl * __expf(ml - mn) + __expf(x - mn);
        ml = mn;
    }
    for (int off = H; off < 64; off <<= 1) {
        float mo = __shfl_xor(ml, off);
        float so = __shfl_xor(sl, off);
        float mn = fmaxf(ml, mo);
        float t1 = (ml > -INFINITY) ? sl * __expf(ml - mn) : 0.f;
        float t2 = (mo > -INFINITY) ? so * __expf(mo - mn) : 0.f;
        sl = t1 + t2;
        ml = mn;
    }

    int c = lane & (HD - 1);
    int h2 = c / D;
    float m2 = __shfl(ml, h2);
    float s2 = __shfl(sl, h2);
    float xd2 = ald[node * H + h2];
    float a0 = 0.f, a1 = 0.f, a2 = 0.f, a3 = 0.f;
    int k = lane / HD;
    for (; k + 3 * EG < cnt; k += 4 * EG) {
        int sn0 = csr_src[row + k];
        int sn1 = csr_src[row + k + EG];
        int sn2 = csr_src[row + k + 2 * EG];
        int sn3 = csr_src[row + k + 3 * EG];
        float x0 = als[sn0 * H + h2] + xd2;
        float x1 = als[sn1 * H + h2] + xd2;
        float x2 = als[sn2 * H + h2] + xd2;
        float x3 = als[sn3 * H + h2] + xd2;
        x0 = (x0 > 0.f) ? x0 : NEG_SLOPE * x0;
        x1 = (x1 > 0.f) ? x1 : NEG_SLOPE * x1;
        x2 = (x2 > 0.f) ? x2 : NEG_SLOPE * x2;
        x3 = (x3 > 0.f) ? x3 : NEG_SLOPE * x3;
        float w0 = __expf(x0 - m2);
        float w1 = __expf(x1 - m2);
        float w2 = __expf(x2 - m2);
        float w3 = __expf(x3 - m2);
        a0 = fmaf(w0, hfeat[(size_t)sn0 * HD + c], a0);
        a1 = fmaf(w1, hfeat[(size_t)sn1 * HD + c], a1);
        a2 = fmaf(w2, hfeat[(size_t)sn2 * HD + c], a2);
        a3 = fmaf(w3, hfeat[(size_t)sn3 * HD + c], a3);
    }
    for (; k < cnt; k += EG) {
        int sn = csr_src[row + k];
        float x = als[sn * H + h2] + xd2;
        x = (x > 0.f) ? x : NEG_SLOPE * x;
        a0 = fmaf(__expf(x - m2), hfeat[(size_t)sn * HD + c], a0);
    }
    float acc = (a0 + a1) + (a2 + a3);
    for (int off = HD; off < 64; off <<= 1) acc += __shfl_xor(acc, off);
    if (lane < HD) {
        float v = acc / s2 + bias[c];
        if (RELU) v = fmaxf(v, 0.f);
        out[(size_t)node * HD + c] = v;
    }
}

// ============================================================================

extern "C" void kernel_launch(void* const* d_in, const int* in_sizes, int n_in,
                              void* d_out, int out_size, void* d_ws, size_t ws_size,
                              hipStream_t stream) {
    const float* x   = (const float*)d_in[0];
    const int*   ei  = (const int*)d_in[1];
    const float* W1  = (const float*)d_in[2];
    const float* a1s = (const float*)d_in[3];
    const float* a1d = (const float*)d_in[4];
    const float* b1  = (const float*)d_in[5];
    const float* W2  = (const float*)d_in[6];
    const float* a2s = (const float*)d_in[7];
    const float* a2d = (const float*)d_in[8];
    const float* b2  = (const float*)d_in[9];
    const float* W3  = (const float*)d_in[10];
    const float* a3s = (const float*)d_in[11];
    const float* a3d = (const float*)d_in[12];
    const float* b3  = (const float*)d_in[13];
    const float* W4  = (const float*)d_in[14];
    const float* a4s = (const float*)d_in[15];
    const float* a4d = (const float*)d_in[16];
    const float* b4  = (const float*)d_in[17];

    const int N = in_sizes[0] / 128;  // 50000
    const int E = in_sizes[1] / 2;    // 1600000
    const int ET = E + N;             // + self loops
    const int* src = ei;
    const int* dst = ei + E;
    const int NBK = (N + 255) >> 8;   // 196 buckets of 256 dst nodes

    // ---- workspace layout ----
    float* hb    = (float*)d_ws;                    // N*64 fp32 (layer4) / N*64 bf16 (layers 1-3)
    float* bufA  = hb + (size_t)N * 64;             // N*64
    float* als   = bufA + (size_t)N * 64;           // N*8
    float* ald   = als + (size_t)N * 8;             // N*8
    int* offs    = (int*)(ald + (size_t)N * 8);     // N
    int* deg     = offs + N;                        // N
    unsigned* gcursor = (unsigned*)(deg + N);       // 256 (memset 0)
    unsigned* slab = gcursor + 256;                 // NBK*BCAP (csr in place)
    float* out = (float*)d_out;                     // N*16

    __hip_bfloat16* hb16 = (__hip_bfloat16*)hb;

    const int TB = 256;
    const int NODE_BLOCKS = cdiv(N, 4);  // one wave per node, 4 waves/block

    // ---- build dst-CSR: radix partition + per-bucket finalize ----
    hipMemsetAsync(gcursor, 0, 256 * 4, stream);
    partition_kernel<<<cdiv(ET, PT_CHUNK), PT_THREADS, 0, stream>>>(src, dst, gcursor, slab, E, ET, NBK);
    finalize_kernel<<<NBK, 512, 0, stream>>>(gcursor, slab, offs, deg, N);
    const int* csr_src = (const int*)slab;

    // ---- layer 1: x[N,128] -> hb16 -> bufA ----
    gemm_logits_kernel<128, 64, 8, true><<<cdiv(N, 16), TB, 0, stream>>>(x, W1, a1s, a1d, hb16, als, ald, N);
    gat_node8_kernel<true><<<NODE_BLOCKS, TB, 0, stream>>>(hb16, als, ald, offs, deg, csr_src, b1, bufA, N);

    // ---- layer 2: bufA -> hb16 -> bufA ----
    gemm_logits_kernel<64, 64, 8, true><<<cdiv(N, 16), TB, 0, stream>>>(bufA, W2, a2s, a2d, hb16, als, ald, N);
    gat_node8_kernel<true><<<NODE_BLOCKS, TB, 0, stream>>>(hb16, als, ald, offs, deg, csr_src, b2, bufA, N);

    // ---- layer 3: bufA -> hb16 -> bufA ----
    gemm_logits_kernel<64, 64, 8, true><<<cdiv(N, 16), TB, 0, stream>>>(bufA, W3, a3s, a3d, hb16, als, ald, N);
    gat_node8_kernel<true><<<NODE_BLOCKS, TB, 0, stream>>>(hb16, als, ald, offs, deg, csr_src, b3, bufA, N);

    // ---- layer 4: bufA -> hb (fp32) -> d_out (H=1, D=16, no relu) ----
    gemm_logits_kernel<64, 16, 1, false><<<cdiv(N, 64), TB, 0, stream>>>(bufA, W4, a4s, a4d, hb, als, ald, N);
    gat_node_kernel<1, 16, false><<<NODE_BLOCKS, TB, 0, stream>>>(hb, als, ald, offs, deg, csr_src, b4, out, N);
}

// Round 12
// 491.236 us; speedup vs baseline: 1.0971x; 1.0415x over previous
//
#include <hip/hip_runtime.h>
#include <hip/hip_bf16.h>
#include <math.h>

#define NEG_SLOPE 0.2f
#define LOGIT_SHIFT 8.0f   // applied AFTER leaky-relu; softmax-invariant

static inline int cdiv(int a, int b) { return (a + b - 1) / b; }

// ---------------- CSR build: LDS radix partition by dst bucket --------------
#define BCAP 12288
#define PT_THREADS 512
#define PT_EPT 16
#define PT_CHUNK (PT_THREADS * PT_EPT)

__global__ __launch_bounds__(PT_THREADS)
void partition_kernel(const int* __restrict__ src, const int* __restrict__ dst,
                      unsigned* __restrict__ gcursor, unsigned* __restrict__ slab,
                      int E, int ET, int NBK) {
    __shared__ int hist[256];
    __shared__ int lbase[256];
    __shared__ int lcur[256];
    __shared__ int gbase[256];
    __shared__ unsigned stage[PT_CHUNK];
    __shared__ unsigned char binof[PT_CHUNK];

    int base = blockIdx.x * PT_CHUNK;
    int cnt = min(PT_CHUNK, ET - base);

    unsigned vals[PT_EPT];
    short bins[PT_EPT];

    for (int i = threadIdx.x; i < 256; i += PT_THREADS) hist[i] = 0;
    __syncthreads();

#pragma unroll
    for (int i = 0; i < PT_EPT; ++i) {
        int e = base + threadIdx.x + i * PT_THREADS;
        bins[i] = -1;
        if (e < ET) {
            int s = (e < E) ? src[e] : (e - E);
            int d = (e < E) ? dst[e] : (e - E);
            int b = d >> 8;
            vals[i] = ((unsigned)s << 8) | (unsigned)(d & 255);
            bins[i] = (short)b;
            atomicAdd(&hist[b], 1);
        }
    }
    __syncthreads();
    if (threadIdx.x < 256) lbase[threadIdx.x] = hist[threadIdx.x];
    __syncthreads();
    for (int off = 1; off < 256; off <<= 1) {
        int t = 0;
        if (threadIdx.x < 256 && threadIdx.x >= off) t = lbase[threadIdx.x - off];
        __syncthreads();
        if (threadIdx.x < 256) lbase[threadIdx.x] += t;
        __syncthreads();
    }
    if (threadIdx.x < 256) {
        lbase[threadIdx.x] -= hist[threadIdx.x];   // exclusive
        lcur[threadIdx.x] = lbase[threadIdx.x];
        gbase[threadIdx.x] = ((int)threadIdx.x < NBK && hist[threadIdx.x] > 0)
            ? (int)atomicAdd(&gcursor[threadIdx.x], (unsigned)hist[threadIdx.x]) : 0;
    }
    __syncthreads();
#pragma unroll
    for (int i = 0; i < PT_EPT; ++i) {
        if (bins[i] >= 0) {
            int p = atomicAdd(&lcur[bins[i]], 1);
            stage[p] = vals[i];
            binof[p] = (unsigned char)bins[i];
        }
    }
    __syncthreads();
    for (int j = threadIdx.x; j < cnt; j += PT_THREADS) {
        int b = binof[j];
        int idx = gbase[b] + (j - lbase[b]);
        if (idx < BCAP) slab[(size_t)b * BCAP + idx] = stage[j];
    }
}

__global__ __launch_bounds__(512)
void finalize_kernel(const unsigned* __restrict__ gcursor, unsigned* __restrict__ slab,
                     int* __restrict__ offs, int* __restrict__ deg, int N) {
    __shared__ int lhist[256];
    __shared__ int loff[256];
    __shared__ int lcur[256];
    __shared__ unsigned stage[BCAP];
    int b = blockIdx.x;
    int cnt = min((int)gcursor[b], BCAP);
    int d0 = b << 8;
    int nd = min(256, N - d0);
    size_t sb = (size_t)b * BCAP;

    for (int i = threadIdx.x; i < 256; i += 512) lhist[i] = 0;
    __syncthreads();
    for (int i = threadIdx.x; i < cnt; i += 512)
        atomicAdd(&lhist[slab[sb + i] & 255u], 1);
    __syncthreads();
    if (threadIdx.x < 256) loff[threadIdx.x] = lhist[threadIdx.x];
    __syncthreads();
    for (int off = 1; off < 256; off <<= 1) {
        int t = 0;
        if (threadIdx.x < 256 && threadIdx.x >= off) t = loff[threadIdx.x - off];
        __syncthreads();
        if (threadIdx.x < 256) loff[threadIdx.x] += t;
        __syncthreads();
    }
    if (threadIdx.x < 256) {
        loff[threadIdx.x] -= lhist[threadIdx.x];   // exclusive
        lcur[threadIdx.x] = loff[threadIdx.x];
        if ((int)threadIdx.x < nd) {
            offs[d0 + threadIdx.x] = (int)sb + loff[threadIdx.x];
            deg[d0 + threadIdx.x] = lhist[threadIdx.x];
        }
    }
    __syncthreads();
    for (int i = threadIdx.x; i < cnt; i += 512) {
        unsigned v = slab[sb + i];
        int p = atomicAdd(&lcur[v & 255u], 1);
        stage[p] = v >> 8;
    }
    __syncthreads();
    for (int i = threadIdx.x; i < cnt; i += 512)
        slab[sb + i] = stage[i];
}

// ============ dense GEMM + fused attention-logit epilogue ===================
template <int CIN, int COUT, int H, bool BF16OUT>
__global__ void gemm_logits_kernel(const float* __restrict__ in, const float* __restrict__ W,
                                   const float* __restrict__ a_s, const float* __restrict__ a_d,
                                   void* __restrict__ outv, float* __restrict__ als,
                                   float* __restrict__ ald, int N) {
    constexpr int D = COUT / H;
    constexpr int TPN = COUT / 4;
    constexpr int NPB = 256 / TPN;
    __shared__ float xs[NPB * CIN];
    __shared__ float lsum[2][NPB][H];
    int n0 = blockIdx.x * NPB;
    for (int i = threadIdx.x * 4; i < NPB * CIN; i += 256 * 4) {
        int n = n0 + i / CIN;
        float4 v = make_float4(0.f, 0.f, 0.f, 0.f);
        if (n < N) v = *(const float4*)&in[(size_t)n0 * CIN + i];
        *(float4*)&xs[i] = v;
    }
    for (int i = threadIdx.x; i < 2 * NPB * H; i += 256) ((float*)lsum)[i] = 0.f;
    __syncthreads();
    int tn = threadIdx.x / TPN;
    int tc = (threadIdx.x % TPN) * 4;
    int n = n0 + tn;
    if (n < N) {
        const float* xr = xs + tn * CIN;
        float4 a = make_float4(0.f, 0.f, 0.f, 0.f);
#pragma unroll 8
        for (int k = 0; k < CIN; ++k) {
            float xv = xr[k];
            float4 wv = *(const float4*)&W[k * COUT + tc];
            a.x = fmaf(xv, wv.x, a.x);
            a.y = fmaf(xv, wv.y, a.y);
            a.z = fmaf(xv, wv.z, a.z);
            a.w = fmaf(xv, wv.w, a.w);
        }
        if (BF16OUT) {
            __hip_bfloat16* ob = (__hip_bfloat16*)outv;
            ushort4 u;
            u.x = __hip_bfloat16_raw(__float2bfloat16(a.x)).x;
            u.y = __hip_bfloat16_raw(__float2bfloat16(a.y)).x;
            u.z = __hip_bfloat16_raw(__float2bfloat16(a.z)).x;
            u.w = __hip_bfloat16_raw(__float2bfloat16(a.w)).x;
            *(ushort4*)&ob[(size_t)n * COUT + tc] = u;
        } else {
            float* of = (float*)outv;
            *(float4*)&of[(size_t)n * COUT + tc] = a;
        }
        int h = tc / D;
        int dd = tc % D;
        const float* asr = a_s + h * D + dd;
        const float* adr = a_d + h * D + dd;
        float p1 = a.x * asr[0] + a.y * asr[1] + a.z * asr[2] + a.w * asr[3];
        float p2 = a.x * adr[0] + a.y * adr[1] + a.z * adr[2] + a.w * adr[3];
        atomicAdd(&lsum[0][tn][h], p1);
        atomicAdd(&lsum[1][tn][h], p2);
    }
    __syncthreads();
    for (int i = threadIdx.x; i < NPB * H; i += 256) {
        int tn2 = i / H, h2 = i % H;
        int n2 = n0 + tn2;
        if (n2 < N) {
            als[n2 * H + h2] = lsum[0][tn2][h2];
            ald[n2 * H + h2] = lsum[1][tn2][h2];
        }
    }
}

__device__ __forceinline__ float lrelu(float x) {
    return (x > 0.f) ? x : NEG_SLOPE * x;
}
// weight = exp(lrelu(logit) - SHIFT): shift applied POST-activation.
__device__ __forceinline__ float edge_w(float logit) {
    return __expf(lrelu(logit) - LOGIT_SHIFT);
}

// ===== H=8,D=8 aggregate: no-max softmax (post-lrelu shift), pipelined ======
// ONE WAVE PER NODE. lane = (edge_slot el = lane>>3, head hl = lane&7).
template <bool RELU>
__global__ void gat_node8_kernel(const __hip_bfloat16* __restrict__ hfeat,
                                 const float* __restrict__ als, const float* __restrict__ ald,
                                 const int* __restrict__ offs, const int* __restrict__ deg,
                                 const int* __restrict__ csr_src,
                                 const float* __restrict__ bias,
                                 float* __restrict__ out, int N) {
    int lane = threadIdx.x & 63;
    int wid = threadIdx.x >> 6;
    int node = blockIdx.x * (blockDim.x >> 6) + wid;
    if (node >= N) return;
    int row = __builtin_amdgcn_readfirstlane(offs[node]);
    int cnt = __builtin_amdgcn_readfirstlane(deg[node]);

    int hl = lane & 7;
    int el = lane >> 3;
    float xd = ald[node * 8 + hl];

    // ---------- pass 1: s = sum edge_w; iterations independent ----------
    float s0 = 0.f, s1 = 0.f;
    int k = el;
    for (; k + 8 < cnt; k += 16) {
        int snA = csr_src[row + k];
        int snB = csr_src[row + k + 8];
        s0 += edge_w(als[snA * 8 + hl] + xd);
        s1 += edge_w(als[snB * 8 + hl] + xd);
    }
    if (k < cnt) {
        int sn = csr_src[row + k];
        s0 += edge_w(als[sn * 8 + hl] + xd);
    }
    float sl = s0 + s1;
    sl += __shfl_xor(sl, 8);
    sl += __shfl_xor(sl, 16);
    sl += __shfl_xor(sl, 32);
    // lane holds s for head hl

    // ---------- pass 2: acc = sum w * h[src]; software-pipelined ----------
    int c = lane;
    int h2 = lane >> 3;
    float s2 = __shfl(sl, h2);
    float acc = 0.f;
    // prologue: block 0
    int kk = el;
    int kc = (kk < cnt) ? kk : (cnt - 1);
    int sn_l = csr_src[row + kc];
    float w_l = (kk < cnt) ? edge_w(als[sn_l * 8 + hl] + xd) : 0.f;
    for (int kb = 0; kb < cnt; kb += 8) {
        int sn_cur = sn_l;
        float w_cur = w_l;
        int kk2 = kb + 8 + el;
        if (kb + 8 < cnt) {        // prefetch next block while gathering this one
            int kc2 = (kk2 < cnt) ? kk2 : (cnt - 1);
            sn_l = csr_src[row + kc2];
            w_l = (kk2 < cnt) ? edge_w(als[sn_l * 8 + hl] + xd) : 0.f;
        }
#pragma unroll
        for (int e = 0; e < 8; ++e) {
            int srcl = (e << 3) + h2;
            int sn_e = __shfl(sn_cur, srcl);
            float w_e = __shfl(w_cur, srcl);
            float hv = __bfloat162float(hfeat[(size_t)sn_e * 64 + c]);
            acc = fmaf(w_e, hv, acc);
        }
    }
    float v = acc / s2 + bias[c];
    if (RELU) v = fmaxf(v, 0.f);
    out[(size_t)node * 64 + c] = v;
}

// ===== layer-4 aggregate (H=1, D=16, fp32 features), no-max softmax ========
__global__ void gat_node16_kernel(const float* __restrict__ hfeat,
                                  const float* __restrict__ als, const float* __restrict__ ald,
                                  const int* __restrict__ offs, const int* __restrict__ deg,
                                  const int* __restrict__ csr_src,
                                  const float* __restrict__ bias,
                                  float* __restrict__ out, int N) {
    int lane = threadIdx.x & 63;
    int wid = threadIdx.x >> 6;
    int node = blockIdx.x * (blockDim.x >> 6) + wid;
    if (node >= N) return;
    int row = __builtin_amdgcn_readfirstlane(offs[node]);
    int cnt = __builtin_amdgcn_readfirstlane(deg[node]);
    float xd = ald[node];

    // pass 1: sum of edge_w; lanes process strided edges, iters independent
    float s0 = 0.f, s1 = 0.f;
    int k = lane;
    for (; k + 64 < cnt; k += 128) {
        int snA = csr_src[row + k];
        int snB = csr_src[row + k + 64];
        s0 += edge_w(als[snA] + xd);
        s1 += edge_w(als[snB] + xd);
    }
    if (k < cnt) {
        int sn = csr_src[row + k];
        s0 += edge_w(als[sn] + xd);
    }
    float sl = s0 + s1;
#pragma unroll
    for (int off = 1; off < 64; off <<= 1) sl += __shfl_xor(sl, off);

    // pass 2: 4 edge groups (g = lane>>4), c = lane&15; 4-wide unrolled
    int c = lane & 15;
    int g = lane >> 4;
    float a0 = 0.f, a1 = 0.f, a2 = 0.f, a3 = 0.f;
    k = g;
    for (; k + 12 < cnt; k += 16) {
        int sn0 = csr_src[row + k];
        int sn1 = csr_src[row + k + 4];
        int sn2 = csr_src[row + k + 8];
        int sn3 = csr_src[row + k + 12];
        float w0 = edge_w(als[sn0] + xd);
        float w1 = edge_w(als[sn1] + xd);
        float w2 = edge_w(als[sn2] + xd);
        float w3 = edge_w(als[sn3] + xd);
        a0 = fmaf(w0, hfeat[(size_t)sn0 * 16 + c], a0);
        a1 = fmaf(w1, hfeat[(size_t)sn1 * 16 + c], a1);
        a2 = fmaf(w2, hfeat[(size_t)sn2 * 16 + c], a2);
        a3 = fmaf(w3, hfeat[(size_t)sn3 * 16 + c], a3);
    }
    for (; k < cnt; k += 4) {
        int sn = csr_src[row + k];
        a0 = fmaf(edge_w(als[sn] + xd), hfeat[(size_t)sn * 16 + c], a0);
    }
    float acc = (a0 + a1) + (a2 + a3);
    acc += __shfl_xor(acc, 16);
    acc += __shfl_xor(acc, 32);
    if (lane < 16) {
        out[(size_t)node * 16 + c] = acc / sl + bias[c];
    }
}

// ============================================================================

extern "C" void kernel_launch(void* const* d_in, const int* in_sizes, int n_in,
                              void* d_out, int out_size, void* d_ws, size_t ws_size,
                              hipStream_t stream) {
    const float* x   = (const float*)d_in[0];
    const int*   ei  = (const int*)d_in[1];
    const float* W1  = (const float*)d_in[2];
    const float* a1s = (const float*)d_in[3];
    const float* a1d = (const float*)d_in[4];
    const float* b1  = (const float*)d_in[5];
    const float* W2  = (const float*)d_in[6];
    const float* a2s = (const float*)d_in[7];
    const float* a2d = (const float*)d_in[8];
    const float* b2  = (const float*)d_in[9];
    const float* W3  = (const float*)d_in[10];
    const float* a3s = (const float*)d_in[11];
    const float* a3d = (const float*)d_in[12];
    const float* b3  = (const float*)d_in[13];
    const float* W4  = (const float*)d_in[14];
    const float* a4s = (const float*)d_in[15];
    const float* a4d = (const float*)d_in[16];
    const float* b4  = (const float*)d_in[17];

    const int N = in_sizes[0] / 128;  // 50000
    const int E = in_sizes[1] / 2;    // 1600000
    const int ET = E + N;             // + self loops
    const int* src = ei;
    const int* dst = ei + E;
    const int NBK = (N + 255) >> 8;

    // ---- workspace layout ----
    float* hb    = (float*)d_ws;                    // N*64 fp32 (layer4) / bf16 (1-3)
    float* bufA  = hb + (size_t)N * 64;             // N*64
    float* als   = bufA + (size_t)N * 64;           // N*8
    float* ald   = als + (size_t)N * 8;             // N*8
    int* offs    = (int*)(ald + (size_t)N * 8);     // N
    int* deg     = offs + N;                        // N
    unsigned* gcursor = (unsigned*)(deg + N);       // 256 (memset 0)
    unsigned* slab = gcursor + 256;                 // NBK*BCAP
    float* out = (float*)d_out;                     // N*16

    __hip_bfloat16* hb16 = (__hip_bfloat16*)hb;

    const int TB = 256;
    const int NODE_BLOCKS = cdiv(N, 4);

    hipMemsetAsync(gcursor, 0, 256 * 4, stream);
    partition_kernel<<<cdiv(ET, PT_CHUNK), PT_THREADS, 0, stream>>>(src, dst, gcursor, slab, E, ET, NBK);
    finalize_kernel<<<NBK, 512, 0, stream>>>(gcursor, slab, offs, deg, N);
    const int* csr_src = (const int*)slab;

    // ---- layer 1 ----
    gemm_logits_kernel<128, 64, 8, true><<<cdiv(N, 16), TB, 0, stream>>>(x, W1, a1s, a1d, hb16, als, ald, N);
    gat_node8_kernel<true><<<NODE_BLOCKS, TB, 0, stream>>>(hb16, als, ald, offs, deg, csr_src, b1, bufA, N);

    // ---- layer 2 ----
    gemm_logits_kernel<64, 64, 8, true><<<cdiv(N, 16), TB, 0, stream>>>(bufA, W2, a2s, a2d, hb16, als, ald, N);
    gat_node8_kernel<true><<<NODE_BLOCKS, TB, 0, stream>>>(hb16, als, ald, offs, deg, csr_src, b2, bufA, N);

    // ---- layer 3 ----
    gemm_logits_kernel<64, 64, 8, true><<<cdiv(N, 16), TB, 0, stream>>>(bufA, W3, a3s, a3d, hb16, als, ald, N);
    gat_node8_kernel<true><<<NODE_BLOCKS, TB, 0, stream>>>(hb16, als, ald, offs, deg, csr_src, b3, bufA, N);

    // ---- layer 4 ----
    gemm_logits_kernel<64, 16, 1, false><<<cdiv(N, 64), TB, 0, stream>>>(bufA, W4, a4s, a4d, hb, als, ald, N);
    gat_node16_kernel<<<NODE_BLOCKS, TB, 0, stream>>>(hb, als, ald, offs, deg, csr_src, b4, out, N);
}

// Round 14
// 411.475 us; speedup vs baseline: 1.3097x; 1.1938x over previous
//
#include <hip/hip_runtime.h>
#include <hip/hip_bf16.h>
#include <math.h>

#define NEG_SLOPE 0.2f
#define LOGIT_SHIFT 8.0f   // applied AFTER leaky-relu; softmax-invariant

static inline int cdiv(int a, int b) { return (a + b - 1) / b; }

// ---------------- CSR build: LDS radix partition by dst bucket --------------
#define BCAP 12288
#define PT_THREADS 512
#define PT_EPT 16
#define PT_CHUNK (PT_THREADS * PT_EPT)

__global__ __launch_bounds__(PT_THREADS)
void partition_kernel(const int* __restrict__ src, const int* __restrict__ dst,
                      unsigned* __restrict__ gcursor, unsigned* __restrict__ slab,
                      int E, int ET, int NBK) {
    __shared__ int hist[256];
    __shared__ int lbase[256];
    __shared__ int lcur[256];
    __shared__ int gbase[256];
    __shared__ unsigned stage[PT_CHUNK];
    __shared__ unsigned char binof[PT_CHUNK];

    int base = blockIdx.x * PT_CHUNK;
    int cnt = min(PT_CHUNK, ET - base);

    unsigned vals[PT_EPT];
    short bins[PT_EPT];

    for (int i = threadIdx.x; i < 256; i += PT_THREADS) hist[i] = 0;
    __syncthreads();

#pragma unroll
    for (int i = 0; i < PT_EPT; ++i) {
        int e = base + threadIdx.x + i * PT_THREADS;
        bins[i] = -1;
        if (e < ET) {
            int s = (e < E) ? src[e] : (e - E);
            int d = (e < E) ? dst[e] : (e - E);
            int b = d >> 8;
            vals[i] = ((unsigned)s << 8) | (unsigned)(d & 255);
            bins[i] = (short)b;
            atomicAdd(&hist[b], 1);
        }
    }
    __syncthreads();
    if (threadIdx.x < 256) lbase[threadIdx.x] = hist[threadIdx.x];
    __syncthreads();
    for (int off = 1; off < 256; off <<= 1) {
        int t = 0;
        if (threadIdx.x < 256 && threadIdx.x >= off) t = lbase[threadIdx.x - off];
        __syncthreads();
        if (threadIdx.x < 256) lbase[threadIdx.x] += t;
        __syncthreads();
    }
    if (threadIdx.x < 256) {
        lbase[threadIdx.x] -= hist[threadIdx.x];   // exclusive
        lcur[threadIdx.x] = lbase[threadIdx.x];
        gbase[threadIdx.x] = ((int)threadIdx.x < NBK && hist[threadIdx.x] > 0)
            ? (int)atomicAdd(&gcursor[threadIdx.x], (unsigned)hist[threadIdx.x]) : 0;
    }
    __syncthreads();
#pragma unroll
    for (int i = 0; i < PT_EPT; ++i) {
        if (bins[i] >= 0) {
            int p = atomicAdd(&lcur[bins[i]], 1);
            stage[p] = vals[i];
            binof[p] = (unsigned char)bins[i];
        }
    }
    __syncthreads();
    for (int j = threadIdx.x; j < cnt; j += PT_THREADS) {
        int b = binof[j];
        int idx = gbase[b] + (j - lbase[b]);
        if (idx < BCAP) slab[(size_t)b * BCAP + idx] = stage[j];
    }
}

__global__ __launch_bounds__(512)
void finalize_kernel(const unsigned* __restrict__ gcursor, unsigned* __restrict__ slab,
                     int* __restrict__ offs, int* __restrict__ deg, int N) {
    __shared__ int lhist[256];
    __shared__ int loff[256];
    __shared__ int lcur[256];
    __shared__ unsigned stage[BCAP];
    int b = blockIdx.x;
    int cnt = min((int)gcursor[b], BCAP);
    int d0 = b << 8;
    int nd = min(256, N - d0);
    size_t sb = (size_t)b * BCAP;

    for (int i = threadIdx.x; i < 256; i += 512) lhist[i] = 0;
    __syncthreads();
    for (int i = threadIdx.x; i < cnt; i += 512)
        atomicAdd(&lhist[slab[sb + i] & 255u], 1);
    __syncthreads();
    if (threadIdx.x < 256) loff[threadIdx.x] = lhist[threadIdx.x];
    __syncthreads();
    for (int off = 1; off < 256; off <<= 1) {
        int t = 0;
        if (threadIdx.x < 256 && threadIdx.x >= off) t = loff[threadIdx.x - off];
        __syncthreads();
        if (threadIdx.x < 256) loff[threadIdx.x] += t;
        __syncthreads();
    }
    if (threadIdx.x < 256) {
        loff[threadIdx.x] -= lhist[threadIdx.x];   // exclusive
        lcur[threadIdx.x] = loff[threadIdx.x];
        if ((int)threadIdx.x < nd) {
            offs[d0 + threadIdx.x] = (int)sb + loff[threadIdx.x];
            deg[d0 + threadIdx.x] = lhist[threadIdx.x];
        }
    }
    __syncthreads();
    for (int i = threadIdx.x; i < cnt; i += 512) {
        unsigned v = slab[sb + i];
        int p = atomicAdd(&lcur[v & 255u], 1);
        stage[p] = v >> 8;
    }
    __syncthreads();
    for (int i = threadIdx.x; i < cnt; i += 512)
        slab[sb + i] = stage[i];
}

// ============ dense GEMM + fused attention-logit epilogue ===================
template <int CIN, int COUT, int H, bool BF16OUT>
__global__ void gemm_logits_kernel(const float* __restrict__ in, const float* __restrict__ W,
                                   const float* __restrict__ a_s, const float* __restrict__ a_d,
                                   void* __restrict__ outv, float* __restrict__ als,
                                   float* __restrict__ ald, int N) {
    constexpr int D = COUT / H;
    constexpr int TPN = COUT / 4;
    constexpr int NPB = 256 / TPN;
    __shared__ float xs[NPB * CIN];
    __shared__ float lsum[2][NPB][H];
    int n0 = blockIdx.x * NPB;
    for (int i = threadIdx.x * 4; i < NPB * CIN; i += 256 * 4) {
        int n = n0 + i / CIN;
        float4 v = make_float4(0.f, 0.f, 0.f, 0.f);
        if (n < N) v = *(const float4*)&in[(size_t)n0 * CIN + i];
        *(float4*)&xs[i] = v;
    }
    for (int i = threadIdx.x; i < 2 * NPB * H; i += 256) ((float*)lsum)[i] = 0.f;
    __syncthreads();
    int tn = threadIdx.x / TPN;
    int tc = (threadIdx.x % TPN) * 4;
    int n = n0 + tn;
    if (n < N) {
        const float* xr = xs + tn * CIN;
        float4 a = make_float4(0.f, 0.f, 0.f, 0.f);
#pragma unroll 8
        for (int k = 0; k < CIN; ++k) {
            float xv = xr[k];
            float4 wv = *(const float4*)&W[k * COUT + tc];
            a.x = fmaf(xv, wv.x, a.x);
            a.y = fmaf(xv, wv.y, a.y);
            a.z = fmaf(xv, wv.z, a.z);
            a.w = fmaf(xv, wv.w, a.w);
        }
        if (BF16OUT) {
            __hip_bfloat16* ob = (__hip_bfloat16*)outv;
            ushort4 u;
            u.x = __hip_bfloat16_raw(__float2bfloat16(a.x)).x;
            u.y = __hip_bfloat16_raw(__float2bfloat16(a.y)).x;
            u.z = __hip_bfloat16_raw(__float2bfloat16(a.z)).x;
            u.w = __hip_bfloat16_raw(__float2bfloat16(a.w)).x;
            *(ushort4*)&ob[(size_t)n * COUT + tc] = u;
        } else {
            float* of = (float*)outv;
            *(float4*)&of[(size_t)n * COUT + tc] = a;
        }
        int h = tc / D;
        int dd = tc % D;
        const float* asr = a_s + h * D + dd;
        const float* adr = a_d + h * D + dd;
        float p1 = a.x * asr[0] + a.y * asr[1] + a.z * asr[2] + a.w * asr[3];
        float p2 = a.x * adr[0] + a.y * adr[1] + a.z * adr[2] + a.w * adr[3];
        atomicAdd(&lsum[0][tn][h], p1);
        atomicAdd(&lsum[1][tn][h], p2);
    }
    __syncthreads();
    for (int i = threadIdx.x; i < NPB * H; i += 256) {
        int tn2 = i / H, h2 = i % H;
        int n2 = n0 + tn2;
        if (n2 < N) {
            als[n2 * H + h2] = lsum[0][tn2][h2];
            ald[n2 * H + h2] = lsum[1][tn2][h2];
        }
    }
}

__device__ __forceinline__ float lrelu(float x) {
    return (x > 0.f) ? x : NEG_SLOPE * x;
}
// weight = exp(lrelu(logit) - SHIFT): shift applied POST-activation.
__device__ __forceinline__ float edge_w(float logit) {
    return __expf(lrelu(logit) - LOGIT_SHIFT);
}

// ===== H=8,D=8 aggregate: SINGLE PASS, vector gathers, no in-loop shuffles ==
// ONE WAVE PER NODE. lane = (edge_slot el = lane>>3, head/ch-block cb = lane&7).
// Each lane: computes w(edge el+8t, head cb) in-lane, loads 16 B (8 bf16) of
// that edge's features for channels cb*8..cb*8+7, accumulates acc[8] and s.
// End: reduce (s, acc[8]) across el via 27 shfl_xor; lanes 0-7 write.
template <bool RELU>
__global__ void gat_node8_kernel(const __hip_bfloat16* __restrict__ hfeat,
                                 const float* __restrict__ als, const float* __restrict__ ald,
                                 const int* __restrict__ offs, const int* __restrict__ deg,
                                 const int* __restrict__ csr_src,
                                 const float* __restrict__ bias,
                                 float* __restrict__ out, int N) {
    int lane = threadIdx.x & 63;
    int wid = threadIdx.x >> 6;
    int node = blockIdx.x * (blockDim.x >> 6) + wid;
    if (node >= N) return;
    int row = __builtin_amdgcn_readfirstlane(offs[node]);
    int cnt = __builtin_amdgcn_readfirstlane(deg[node]);

    int el = lane >> 3;    // edge slot 0..7
    int cb = lane & 7;     // head == channel block (D=8)
    float xd = ald[node * 8 + cb];

    float s = 0.f;
    float acc[8];
#pragma unroll
    for (int j = 0; j < 8; ++j) acc[j] = 0.f;

    // ---- software-pipelined single pass over edges ----
    int kk = el;
    int kc = (kk < cnt) ? kk : (cnt - 1);   // cnt >= 1 (self-loop)
    int sn_c = csr_src[row + kc];
    float al_c = als[sn_c * 8 + cb];
    uint4 hv_c = *(const uint4*)(hfeat + (size_t)sn_c * 64 + cb * 8);
    bool va_c = (kk < cnt);

    for (int kb = 0; kb < cnt; kb += 8) {
        int sn_n = sn_c; float al_n = 0.f; uint4 hv_n = hv_c; bool va_n = false;
        if (kb + 8 < cnt) {            // prefetch next block
            int kk2 = kb + 8 + el;
            int kc2 = (kk2 < cnt) ? kk2 : (cnt - 1);
            sn_n = csr_src[row + kc2];
            al_n = als[sn_n * 8 + cb];
            hv_n = *(const uint4*)(hfeat + (size_t)sn_n * 64 + cb * 8);
            va_n = (kk2 < cnt);
        }
        float w = va_c ? edge_w(al_c + xd) : 0.f;
        s += w;
        const ushort* hu = (const ushort*)&hv_c;
#pragma unroll
        for (int j = 0; j < 8; ++j) {
            float f = __uint_as_float(((unsigned)hu[j]) << 16);  // bf16 -> f32
            acc[j] = fmaf(w, f, acc[j]);
        }
        sn_c = sn_n; al_c = al_n; hv_c = hv_n; va_c = va_n;
    }

    // ---- reduce across edge slots (lanes differing in bits 3..5) ----
    s += __shfl_xor(s, 8); s += __shfl_xor(s, 16); s += __shfl_xor(s, 32);
#pragma unroll
    for (int j = 0; j < 8; ++j) {
        acc[j] += __shfl_xor(acc[j], 8);
        acc[j] += __shfl_xor(acc[j], 16);
        acc[j] += __shfl_xor(acc[j], 32);
    }

    if (el == 0) {   // lanes 0..7; lane index == cb
        float inv = 1.f / s;
        float o[8];
#pragma unroll
        for (int j = 0; j < 8; ++j) {
            float v = acc[j] * inv + bias[cb * 8 + j];
            if (RELU) v = fmaxf(v, 0.f);
            o[j] = v;
        }
        float4* op = (float4*)(out + (size_t)node * 64 + cb * 8);
        op[0] = make_float4(o[0], o[1], o[2], o[3]);
        op[1] = make_float4(o[4], o[5], o[6], o[7]);
    }
}

// ===== layer-4 aggregate (H=1, D=16, fp32): single pass, float4 gathers =====
// lane = (el = lane>>2 in 0..15, cq = lane&3). Each lane loads float4 of
// channels cq*4..cq*4+3 for edge el+16t; w computed in-lane (H=1).
__global__ void gat_node16_kernel(const float* __restrict__ hfeat,
                                  const float* __restrict__ als, const float* __restrict__ ald,
                                  const int* __restrict__ offs, const int* __restrict__ deg,
                                  const int* __restrict__ csr_src,
                                  const float* __restrict__ bias,
                                  float* __restrict__ out, int N) {
    int lane = threadIdx.x & 63;
    int wid = threadIdx.x >> 6;
    int node = blockIdx.x * (blockDim.x >> 6) + wid;
    if (node >= N) return;
    int row = __builtin_amdgcn_readfirstlane(offs[node]);
    int cnt = __builtin_amdgcn_readfirstlane(deg[node]);

    int el = lane >> 2;    // edge slot 0..15
    int cq = lane & 3;     // channel quad
    float xd = ald[node];

    float s = 0.f;
    float4 acc = make_float4(0.f, 0.f, 0.f, 0.f);

    int kk = el;
    int kc = (kk < cnt) ? kk : (cnt - 1);
    int sn_c = csr_src[row + kc];
    float al_c = als[sn_c];
    float4 hv_c = *(const float4*)(hfeat + (size_t)sn_c * 16 + cq * 4);
    bool va_c = (kk < cnt);

    for (int kb = 0; kb < cnt; kb += 16) {
        int sn_n = sn_c; float al_n = 0.f; float4 hv_n = hv_c; bool va_n = false;
        if (kb + 16 < cnt) {
            int kk2 = kb + 16 + el;
            int kc2 = (kk2 < cnt) ? kk2 : (cnt - 1);
            sn_n = csr_src[row + kc2];
            al_n = als[sn_n];
            hv_n = *(const float4*)(hfeat + (size_t)sn_n * 16 + cq * 4);
            va_n = (kk2 < cnt);
        }
        float w = va_c ? edge_w(al_c + xd) : 0.f;
        s += w;
        acc.x = fmaf(w, hv_c.x, acc.x);
        acc.y = fmaf(w, hv_c.y, acc.y);
        acc.z = fmaf(w, hv_c.z, acc.z);
        acc.w = fmaf(w, hv_c.w, acc.w);
        sn_c = sn_n; al_c = al_n; hv_c = hv_n; va_c = va_n;
    }

    // reduce across el (lanes differing in bits 2..5)
    s += __shfl_xor(s, 4); s += __shfl_xor(s, 8); s += __shfl_xor(s, 16); s += __shfl_xor(s, 32);
#pragma unroll
    for (int r = 4; r < 64; r <<= 1) {
        acc.x += __shfl_xor(acc.x, r);
        acc.y += __shfl_xor(acc.y, r);
        acc.z += __shfl_xor(acc.z, r);
        acc.w += __shfl_xor(acc.w, r);
    }

    if (el == 0) {   // lanes 0..3; lane == cq
        float inv = 1.f / s;
        float4 o;
        o.x = acc.x * inv + bias[cq * 4 + 0];
        o.y = acc.y * inv + bias[cq * 4 + 1];
        o.z = acc.z * inv + bias[cq * 4 + 2];
        o.w = acc.w * inv + bias[cq * 4 + 3];
        *(float4*)(out + (size_t)node * 16 + cq * 4) = o;
    }
}

// ============================================================================

extern "C" void kernel_launch(void* const* d_in, const int* in_sizes, int n_in,
                              void* d_out, int out_size, void* d_ws, size_t ws_size,
                              hipStream_t stream) {
    const float* x   = (const float*)d_in[0];
    const int*   ei  = (const int*)d_in[1];
    const float* W1  = (const float*)d_in[2];
    const float* a1s = (const float*)d_in[3];
    const float* a1d = (const float*)d_in[4];
    const float* b1  = (const float*)d_in[5];
    const float* W2  = (const float*)d_in[6];
    const float* a2s = (const float*)d_in[7];
    const float* a2d = (const float*)d_in[8];
    const float* b2  = (const float*)d_in[9];
    const float* W3  = (const float*)d_in[10];
    const float* a3s = (const float*)d_in[11];
    const float* a3d = (const float*)d_in[12];
    const float* b3  = (const float*)d_in[13];
    const float* W4  = (const float*)d_in[14];
    const float* a4s = (const float*)d_in[15];
    const float* a4d = (const float*)d_in[16];
    const float* b4  = (const float*)d_in[17];

    const int N = in_sizes[0] / 128;  // 50000
    const int E = in_sizes[1] / 2;    // 1600000
    const int ET = E + N;             // + self loops
    const int* src = ei;
    const int* dst = ei + E;
    const int NBK = (N + 255) >> 8;

    // ---- workspace layout ----
    float* hb    = (float*)d_ws;                    // N*64 fp32 (layer4) / bf16 (1-3)
    float* bufA  = hb + (size_t)N * 64;             // N*64
    float* als   = bufA + (size_t)N * 64;           // N*8
    float* ald   = als + (size_t)N * 8;             // N*8
    int* offs    = (int*)(ald + (size_t)N * 8);     // N
    int* deg     = offs + N;                        // N
    unsigned* gcursor = (unsigned*)(deg + N);       // 256 (memset 0)
    unsigned* slab = gcursor + 256;                 // NBK*BCAP
    float* out = (float*)d_out;                     // N*16

    __hip_bfloat16* hb16 = (__hip_bfloat16*)hb;

    const int TB = 256;
    const int NODE_BLOCKS = cdiv(N, 4);

    hipMemsetAsync(gcursor, 0, 256 * 4, stream);
    partition_kernel<<<cdiv(ET, PT_CHUNK), PT_THREADS, 0, stream>>>(src, dst, gcursor, slab, E, ET, NBK);
    finalize_kernel<<<NBK, 512, 0, stream>>>(gcursor, slab, offs, deg, N);
    const int* csr_src = (const int*)slab;

    // ---- layer 1 ----
    gemm_logits_kernel<128, 64, 8, true><<<cdiv(N, 16), TB, 0, stream>>>(x, W1, a1s, a1d, hb16, als, ald, N);
    gat_node8_kernel<true><<<NODE_BLOCKS, TB, 0, stream>>>(hb16, als, ald, offs, deg, csr_src, b1, bufA, N);

    // ---- layer 2 ----
    gemm_logits_kernel<64, 64, 8, true><<<cdiv(N, 16), TB, 0, stream>>>(bufA, W2, a2s, a2d, hb16, als, ald, N);
    gat_node8_kernel<true><<<NODE_BLOCKS, TB, 0, stream>>>(hb16, als, ald, offs, deg, csr_src, b2, bufA, N);

    // ---- layer 3 ----
    gemm_logits_kernel<64, 64, 8, true><<<cdiv(N, 16), TB, 0, stream>>>(bufA, W3, a3s, a3d, hb16, als, ald, N);
    gat_node8_kernel<true><<<NODE_BLOCKS, TB, 0, stream>>>(hb16, als, ald, offs, deg, csr_src, b3, bufA, N);

    // ---- layer 4 ----
    gemm_logits_kernel<64, 16, 1, false><<<cdiv(N, 64), TB, 0, stream>>>(bufA, W4, a4s, a4d, hb, als, ald, N);
    gat_node16_kernel<<<NODE_BLOCKS, TB, 0, stream>>>(hb, als, ald, offs, deg, csr_src, b4, out, N);
}